// Round 1
// 878.404 us; speedup vs baseline: 1.2448x; 1.2448x over previous
//
#include <hip/hip_runtime.h>

typedef unsigned short u16;
typedef __attribute__((ext_vector_type(8))) short bf16x8;
typedef __attribute__((ext_vector_type(4))) float f32x4;

#define GK 4096
#define GN 4096
#define BDIM 4096
#define BROWS 8192

__device__ __forceinline__ u16 f2b(float f) {
    union { float f; unsigned u; } c; c.f = f;
    unsigned u = c.u;
    return (u16)((u + 0x7FFFu + ((u >> 16) & 1u)) >> 16);
}
__device__ __forceinline__ float b2f(u16 h) {
    union { unsigned u; float f; } c; c.u = ((unsigned)h) << 16;
    return c.f;
}
__device__ __forceinline__ void gload16(const void* g, void* l) {
    __builtin_amdgcn_global_load_lds((const __attribute__((address_space(1))) void*)g,
                                     (__attribute__((address_space(3))) void*)l, 16, 0, 0);
}

// ---- convert x -> bf16 + column sums (for mean) ----
__global__ void k_cvt_colsum(const float* __restrict__ x, u16* __restrict__ xb,
                             float* __restrict__ colsum) {
    const int tid  = threadIdx.x;
    const int c4   = blockIdx.x * 64 + (tid & 63);   // float4-column 0..1023
    const int rowg = tid >> 6;                        // 0..3
    const int r0   = blockIdx.y * 128;
    const float4* x4 = (const float4*)x;
    float sx = 0.f, sy = 0.f, sz = 0.f, sw = 0.f;
    for (int i = 0; i < 32; ++i) {
        int row = r0 + i * 4 + rowg;
        float4 v = x4[(size_t)row * 1024 + c4];
        sx += v.x; sy += v.y; sz += v.z; sw += v.w;
        ushort4 o; o.x = f2b(v.x); o.y = f2b(v.y); o.z = f2b(v.z); o.w = f2b(v.w);
        *(ushort4*)(xb + (size_t)row * BDIM + c4 * 4) = o;
    }
    __shared__ float red[256][4];
    red[tid][0] = sx; red[tid][1] = sy; red[tid][2] = sz; red[tid][3] = sw;
    __syncthreads();
    if (tid < 64) {
        for (int j = 64; j < 256; j += 64) {
            sx += red[tid + j][0]; sy += red[tid + j][1];
            sz += red[tid + j][2]; sw += red[tid + j][3];
        }
        int c = blockIdx.x * 64 + tid;
        atomicAdd(&colsum[c * 4 + 0], sx);
        atomicAdd(&colsum[c * 4 + 1], sy);
        atomicAdd(&colsum[c * 4 + 2], sz);
        atomicAdd(&colsum[c * 4 + 3], sw);
    }
}

// ---- both weight matrices f32 -> bf16 in one launch ----
__global__ void k_cvt2(const float4* __restrict__ a, ushort4* __restrict__ ao,
                       const float4* __restrict__ b, ushort4* __restrict__ bo) {
    int i = blockIdx.x * 256 + threadIdx.x;
    const float4* in;  ushort4* out;
    if (i < 4194304) { in = a; out = ao; }
    else             { in = b; out = bo; i -= 4194304; }
    float4 v = in[i];
    ushort4 o; o.x = f2b(v.x); o.y = f2b(v.y); o.z = f2b(v.z); o.w = f2b(v.w);
    out[i] = o;
}

// ---- scalar chain -> sc[0]=crystal_osc, sc[1]=ef*0.3, sc[2]=tb*0.15 ----
__global__ void k_scalars(const float* __restrict__ colsum, const float* __restrict__ Wf,
                          const float* __restrict__ bfp, const float* __restrict__ pmem,
                          const float* __restrict__ cmom, const int* __restrict__ tstep,
                          float* __restrict__ sc) {
    const int tid = threadIdx.x;
    float s = 0.f;
    for (int i = tid; i < BDIM; i += 256) s += Wf[i] * colsum[i];
    __shared__ float red[256];
    red[tid] = s; __syncthreads();
    for (int off = 128; off > 0; off >>= 1) {
        if (tid < off) red[tid] += red[tid + off];
        __syncthreads();
    }
    if (tid == 0) {
        const float TP = 6.283185307179586f;
        float mdot = red[0] * (1.f / (float)BROWS) + bfp[0];
        float fa = 1.f / (1.f + expf(-mdot));
        int ts = tstep[0] + 1;
        float t = (float)ts / 100.f;
        float af = 1.618033f * (1.f + fa * 0.2f);
        float pp = fmodf(TP * t * af, TP);
        float sp = fmodf(pp / 1.618033f, TP);
        float co = 0.3f * (sinf(pp) + 0.3f * cosf(sp));
        float d[25];
        d[0] = pp - pmem[0];
        for (int j = 1; j < 25; ++j) d[j] = pmem[2 * j - 1] - pmem[2 * j];
        float m = 0.f;
        for (int j = 0; j < 25; ++j) m += d[j];
        m *= (1.f / 25.f);
        float var = 0.f;
        for (int j = 0; j < 25; ++j) { float e = d[j] - m; var += e * e; }
        var *= (1.f / 24.f);
        float sd = sqrtf(var);
        float pc = fminf(fmaxf(1.f - sd / TP, 0.f), 1.f);
        float cc = 0.9f * (1.f + pc * 0.2f);
        float stab = fminf((float)ts / 1000.f, 1.f);
        float coh1 = cc * (1.f + stab * 0.3f);
        float nm = 0.98f * cmom[0] + 0.02f * coh1;
        float coh = fminf(fmaxf(nm, 0.72f), 1.35f);
        float tf = 1.f + fminf((float)ts / 5000.f, 0.5f);
        sc[0] = co;
        sc[1] = coh * 1.2f * tf * 0.3f;
        sc[2] = (1.f + coh * 0.2f * tf) * 0.15f;
    }
}

// ---- cs_ef[i] = (0.98*cstate + 0.02*osc*cw*(1+tanh(Wamp@mean+bamp))) * ef*0.3 ----
__global__ void k_csef(const float* __restrict__ Wamp, const float* __restrict__ colsum,
                       const float* __restrict__ bamp, const float* __restrict__ cw,
                       const float* __restrict__ cstate, const float* __restrict__ sc,
                       float* __restrict__ csef) {
    const int row = blockIdx.x, tid = threadIdx.x;
    const float4* w4 = (const float4*)(Wamp + (size_t)row * BDIM);
    const float4* m4 = (const float4*)colsum;
    float s = 0.f;
    for (int i = tid; i < 1024; i += 256) {
        float4 w = w4[i], m = m4[i];
        s += w.x * m.x + w.y * m.y + w.z * m.z + w.w * m.w;
    }
    __shared__ float red[256];
    red[tid] = s; __syncthreads();
    for (int off = 128; off > 0; off >>= 1) {
        if (tid < off) red[tid] += red[tid + off];
        __syncthreads();
    }
    if (tid == 0) {
        float v = red[0] * (1.f / (float)BROWS) + bamp[row];
        float ew = cw[row] * (1.f + tanhf(v));
        float cs = 0.98f * cstate[row] + 0.02f * sc[0] * ew;
        csef[row] = cs * sc[1];
    }
}

// ================= 256x256 8-phase bf16 NT GEMM =================
// Tile 256x256, BK=64, 512 threads = 8 waves (2M x 4N), per-wave C = 128x64.
// LDS: 2 x (A 256x64 + B 256x64) bf16 = 128 KiB double buffer.
// LDS swizzle: row-major [256][64] u16, 16B chunk p at row r holds global
// chunk p ^ (r&7) (proven conflict-free in prior kernel; reads 2-way max).
// Staging (global_load_lds, wave-uniform dest): each wave stages ONLY the
// A-half (wm) and B-half (wn>>1) it reads, 4 x 1KiB windows of each, so its
// own vmcnt covers exactly the regions it consumes; other stagers of the
// same half are covered by (their vmcnt) + s_barrier.
// Window ranks: rA = wn among the 4 same-wm waves; rB = wm*2+(wn&1) among
// the 4 same-B-half waves.
//   A windows (8-row units of the 128-row half): j0:rA  j1:4+rA  j2:8+rA  j3:12+rA
//     -> j0,j1 = half-rows 0-63  (read at P1),  j2,j3 = 64-127 (read at P3)
//   B windows: j0:rB  j1:8+rB  j2:4+rB  j3:12+rB
//     -> j0,j1 = half-rows {0-31,64-95}  (read at P1: wn even / odd)
//        j2,j3 = half-rows {32-63,96-127}(read at P2)
// Issue order per tile T (staging tile T+1): P1:{B0,B1} P2:{A0,A1} P3:{B2,B3} P4:{A2,A3}
// Waits (each leaves 4 loads in flight, >=2-phase issue->wait gap):
//   P1-post vmcnt(4) drains B2,B3(T)   (needed by P2 reads)
//   P2-post vmcnt(4) drains A2,A3(T)   (needed by P3 reads)
//   P4-post vmcnt(4) drains B0,B1,A0,A1(T+1) (needed by T+1.P1 reads)
// Raw s_barrier (no implicit vmcnt drain) + sched_barrier(0) pinning.
template <bool STAGE, int W1, int W2>
__device__ __forceinline__ void gemm_tile(
    const u16* __restrict__ Ab, const u16* __restrict__ Bb,
    u16* __restrict__ An, u16* __restrict__ Bn, int ks,
    const u16* const (&aAg)[4], const u16* const (&bBg)[4],
    const int (&aLd)[4], const int (&bLd)[4],
    int apos, int bpos, int c0, int c1,
    bf16x8 (&a)[4][2], bf16x8 (&q0)[2][2], bf16x8 (&q1)[2][2],
    f32x4 (&acc)[8][4])
{
    // ---------------- P1: mfrags 0-3 x nfrags 0-1 ----------------
#pragma unroll
    for (int f = 0; f < 4; ++f) {
        a[f][0] = *(const bf16x8*)(Ab + apos + f * 1024 + c0);
        a[f][1] = *(const bf16x8*)(Ab + apos + f * 1024 + c1);
    }
#pragma unroll
    for (int f = 0; f < 2; ++f) {
        q0[f][0] = *(const bf16x8*)(Bb + bpos + f * 1024 + c0);
        q0[f][1] = *(const bf16x8*)(Bb + bpos + f * 1024 + c1);
    }
    if constexpr (STAGE) {
        gload16(bBg[0] + ks, Bn + bLd[0]);
        gload16(bBg[1] + ks, Bn + bLd[1]);
    }
    __builtin_amdgcn_s_barrier();
    __builtin_amdgcn_s_setprio(1);
#pragma unroll
    for (int mf = 0; mf < 4; ++mf)
#pragma unroll
        for (int nf = 0; nf < 2; ++nf) {
            acc[mf][nf] = __builtin_amdgcn_mfma_f32_16x16x32_bf16(a[mf][0], q0[nf][0], acc[mf][nf], 0, 0, 0);
            acc[mf][nf] = __builtin_amdgcn_mfma_f32_16x16x32_bf16(a[mf][1], q0[nf][1], acc[mf][nf], 0, 0, 0);
        }
    __builtin_amdgcn_s_setprio(0);
    if constexpr (W1 == 4) asm volatile("s_waitcnt vmcnt(4)" ::: "memory");
    else                   asm volatile("s_waitcnt vmcnt(2)" ::: "memory");
    __builtin_amdgcn_s_barrier();
    __builtin_amdgcn_sched_barrier(0);

    // ---------------- P2: mfrags 0-3 x nfrags 2-3 ----------------
#pragma unroll
    for (int f = 0; f < 2; ++f) {
        q1[f][0] = *(const bf16x8*)(Bb + bpos + (2 + f) * 1024 + c0);
        q1[f][1] = *(const bf16x8*)(Bb + bpos + (2 + f) * 1024 + c1);
    }
    if constexpr (STAGE) {
        gload16(aAg[0] + ks, An + aLd[0]);
        gload16(aAg[1] + ks, An + aLd[1]);
    }
    __builtin_amdgcn_s_barrier();
    __builtin_amdgcn_s_setprio(1);
#pragma unroll
    for (int mf = 0; mf < 4; ++mf)
#pragma unroll
        for (int nf = 0; nf < 2; ++nf) {
            acc[mf][2 + nf] = __builtin_amdgcn_mfma_f32_16x16x32_bf16(a[mf][0], q1[nf][0], acc[mf][2 + nf], 0, 0, 0);
            acc[mf][2 + nf] = __builtin_amdgcn_mfma_f32_16x16x32_bf16(a[mf][1], q1[nf][1], acc[mf][2 + nf], 0, 0, 0);
        }
    __builtin_amdgcn_s_setprio(0);
    if constexpr (W2 == 4) asm volatile("s_waitcnt vmcnt(4)" ::: "memory");
    else                   asm volatile("s_waitcnt vmcnt(0)" ::: "memory");
    __builtin_amdgcn_s_barrier();
    __builtin_amdgcn_sched_barrier(0);

    // ---------------- P3: mfrags 4-7 x nfrags 0-1 ----------------
#pragma unroll
    for (int f = 0; f < 4; ++f) {
        a[f][0] = *(const bf16x8*)(Ab + apos + (4 + f) * 1024 + c0);
        a[f][1] = *(const bf16x8*)(Ab + apos + (4 + f) * 1024 + c1);
    }
    if constexpr (STAGE) {
        gload16(bBg[2] + ks, Bn + bLd[2]);
        gload16(bBg[3] + ks, Bn + bLd[3]);
    }
    __builtin_amdgcn_s_barrier();
    __builtin_amdgcn_s_setprio(1);
#pragma unroll
    for (int mf = 0; mf < 4; ++mf)
#pragma unroll
        for (int nf = 0; nf < 2; ++nf) {
            acc[4 + mf][nf] = __builtin_amdgcn_mfma_f32_16x16x32_bf16(a[mf][0], q0[nf][0], acc[4 + mf][nf], 0, 0, 0);
            acc[4 + mf][nf] = __builtin_amdgcn_mfma_f32_16x16x32_bf16(a[mf][1], q0[nf][1], acc[4 + mf][nf], 0, 0, 0);
        }
    __builtin_amdgcn_s_setprio(0);
    __builtin_amdgcn_s_barrier();
    __builtin_amdgcn_sched_barrier(0);

    // ---------------- P4: mfrags 4-7 x nfrags 2-3 ----------------
    if constexpr (STAGE) {
        gload16(aAg[2] + ks, An + aLd[2]);
        gload16(aAg[3] + ks, An + aLd[3]);
    }
    __builtin_amdgcn_s_barrier();
    __builtin_amdgcn_s_setprio(1);
#pragma unroll
    for (int mf = 0; mf < 4; ++mf)
#pragma unroll
        for (int nf = 0; nf < 2; ++nf) {
            acc[4 + mf][2 + nf] = __builtin_amdgcn_mfma_f32_16x16x32_bf16(a[mf][0], q1[nf][0], acc[4 + mf][2 + nf], 0, 0, 0);
            acc[4 + mf][2 + nf] = __builtin_amdgcn_mfma_f32_16x16x32_bf16(a[mf][1], q1[nf][1], acc[4 + mf][2 + nf], 0, 0, 0);
        }
    __builtin_amdgcn_s_setprio(0);
    if constexpr (STAGE) asm volatile("s_waitcnt vmcnt(4)" ::: "memory");
    __builtin_amdgcn_s_barrier();
    __builtin_amdgcn_sched_barrier(0);
}

// MODE 1: enh_bf = bf16( xf + csef[col] * sigmoid(acc + bias[col]) )
// MODE 2: outf   = b2f(A[row,col]) + tanh(acc + bias[col]) * sc[2]
template <int MODE>
__global__ __launch_bounds__(512, 2) void gemm256(
    const u16* __restrict__ A, const u16* __restrict__ Bm,
    const float* __restrict__ xf, const float* __restrict__ bias,
    const float* __restrict__ csef, const float* __restrict__ sc,
    u16* __restrict__ outb, float* __restrict__ outf)
{
    __shared__ u16 As[2 * 256 * 64];
    __shared__ u16 Bs[2 * 256 * 64];

    const int tid  = threadIdx.x;
    const int lane = tid & 63;
    const int wave = tid >> 6;
    const int wm = wave >> 2;       // 0..1
    const int wn = wave & 3;        // 0..3

    // XCD-aware swizzle: 512 blocks (%8==0), column-major so each XCD chunk
    // (64 consecutive) covers 2 N-tiles x 32 M-tiles -> 4MB B-panel in XCD L2.
    const int bid = blockIdx.x;
    const int swz = (bid & 7) * 64 + (bid >> 3);
    const int bn0 = (swz >> 5) * 256;   // 16 n-tiles
    const int bm0 = (swz & 31) * 256;   // 32 m-tiles

    // ---- staging descriptors ----
    const int lr = lane >> 3, lc = lane & 7;
    const int gch = (lc ^ lr) * 8;               // pre-swizzled global chunk (u16)
    const int rA = wn;
    const int rB = wm * 2 + (wn & 1);
    const int awin[4] = {rA, 4 + rA, 8 + rA, 12 + rA};
    const int bwin[4] = {rB, 8 + rB, 4 + rB, 12 + rB};
    const u16* aAg[4]; const u16* bBg[4];
    int aLd[4], bLd[4];
#pragma unroll
    for (int j = 0; j < 4; ++j) {
        aAg[j] = A  + (size_t)(bm0 + wm * 128 + awin[j] * 8 + lr) * GK + gch;
        bBg[j] = Bm + (size_t)(bn0 + (wn >> 1) * 128 + bwin[j] * 8 + lr) * GK + gch;
        aLd[j] = (wm * 128 + awin[j] * 8) * 64;
        bLd[j] = ((wn >> 1) * 128 + bwin[j] * 8) * 64;
    }

    // ---- ds-read descriptors ----
    const int lm   = lane & 15;
    const int quad = lane >> 4;
    const int rsw  = lm & 7;
    const int apos = (wm * 128 + lm) * 64;
    const int bpos = (wn * 64 + lm) * 64;
    const int c0 = (quad ^ rsw) * 8;
    const int c1 = ((4 + quad) ^ rsw) * 8;

    f32x4 acc[8][4];
#pragma unroll
    for (int i = 0; i < 8; ++i)
#pragma unroll
        for (int j = 0; j < 4; ++j) acc[i][j] = (f32x4){0.f, 0.f, 0.f, 0.f};

    // ---- prologue: stage tile 0 into buf0, same issue order as loop ----
    gload16(bBg[0], Bs + bLd[0]);
    gload16(bBg[1], Bs + bLd[1]);
    gload16(aAg[0], As + aLd[0]);
    gload16(aAg[1], As + aLd[1]);
    gload16(bBg[2], Bs + bLd[2]);
    gload16(bBg[3], Bs + bLd[3]);
    gload16(aAg[2], As + aLd[2]);
    gload16(aAg[3], As + aLd[3]);
    asm volatile("s_waitcnt vmcnt(4)" ::: "memory");   // B0,B1,A0,A1 landed
    __builtin_amdgcn_s_barrier();
    __builtin_amdgcn_sched_barrier(0);

    bf16x8 a[4][2], q0[2][2], q1[2][2];

#pragma unroll 2
    for (int T = 0; T < 63; ++T) {
        const u16* Ab = As + ((T & 1) << 14);
        const u16* Bb = Bs + ((T & 1) << 14);
        u16* An = As + (((T + 1) & 1) << 14);
        u16* Bn = Bs + (((T + 1) & 1) << 14);
        const int ks = (T + 1) * 64;
        gemm_tile<true, 4, 4>(Ab, Bb, An, Bn, ks, aAg, bBg, aLd, bLd,
                              apos, bpos, c0, c1, a, q0, q1, acc);
    }
    // tail tile 63 (buf 1), no staging; tight drains
    gemm_tile<false, 2, 0>(As + (1 << 14), Bs + (1 << 14), As, Bs, 0,
                           aAg, bBg, aLd, bLd, apos, bpos, c0, c1, a, q0, q1, acc);

    // ---- epilogue ----
    const int col0 = bn0 + wn * 64 + lm;
    const int row0 = bm0 + wm * 128 + quad * 4;
    float bias_v[4], csef_v[4];
#pragma unroll
    for (int nf = 0; nf < 4; ++nf) {
        bias_v[nf] = bias[col0 + nf * 16];
        if (MODE == 1) csef_v[nf] = csef[col0 + nf * 16];
    }
    const float tb15 = (MODE == 2) ? sc[2] : 0.f;
#pragma unroll
    for (int mf = 0; mf < 8; ++mf) {
#pragma unroll
        for (int r = 0; r < 4; ++r) {
            const int row = row0 + mf * 16 + r;
#pragma unroll
            for (int nf = 0; nf < 4; ++nf) {
                const int col = col0 + nf * 16;
                const float v = acc[mf][nf][r];
                const size_t idx = (size_t)row * GN + col;
                if (MODE == 1) {
                    float vb = v + bias_v[nf];
                    vb = fminf(fmaxf(vb, -30.f), 30.f);
                    float sg = 1.f / (1.f + __expf(-vb));
                    float e = xf[idx] + csef_v[nf] * sg;
                    outb[idx] = f2b(e);
                } else {
                    float vb = v + bias_v[nf];
                    vb = fminf(fmaxf(vb, -15.f), 15.f);
                    float e2 = __expf(2.f * vb);
                    float th = (e2 - 1.f) / (e2 + 1.f);
                    outf[idx] = b2f(A[idx]) + th * tb15;
                }
            }
        }
    }
}

extern "C" void kernel_launch(void* const* d_in, const int* in_sizes, int n_in,
                              void* d_out, int out_size, void* d_ws, size_t ws_size,
                              hipStream_t stream) {
    const float* x      = (const float*)d_in[0];
    const float* cstate = (const float*)d_in[1];
    const float* pmem   = (const float*)d_in[2];
    const float* cmom   = (const float*)d_in[3];
    const float* cw     = (const float*)d_in[4];
    const float* Wf     = (const float*)d_in[5];
    const float* bfp    = (const float*)d_in[6];
    const float* Wamp   = (const float*)d_in[7];
    const float* bamp   = (const float*)d_in[8];
    const float* Wtemp  = (const float*)d_in[9];
    const float* btemp  = (const float*)d_in[10];
    const float* Wgate  = (const float*)d_in[11];
    const float* bgate  = (const float*)d_in[12];
    const int*   tstep  = (const int*)d_in[13];
    float* out = (float*)d_out;

    char* ws = (char*)d_ws;
    u16* x_bf   = (u16*)ws;  ws += (size_t)BROWS * BDIM * 2;   // 64 MB
    u16* wg_bf  = (u16*)ws;  ws += (size_t)BDIM * BDIM * 2;    // 32 MB
    u16* wt_bf  = (u16*)ws;  ws += (size_t)BDIM * BDIM * 2;    // 32 MB
    u16* enh_bf = (u16*)ws;  ws += (size_t)BROWS * BDIM * 2;   // 64 MB
    float* colsum = (float*)ws; ws += BDIM * 4;
    float* csef   = (float*)ws; ws += BDIM * 4;
    float* sc     = (float*)ws; ws += 256;

    hipMemsetAsync(colsum, 0, BDIM * sizeof(float), stream);
    k_cvt_colsum<<<dim3(16, 64), 256, 0, stream>>>(x, x_bf, colsum);
    k_cvt2<<<32768, 256, 0, stream>>>((const float4*)Wgate, (ushort4*)wg_bf,
                                      (const float4*)Wtemp, (ushort4*)wt_bf);
    k_scalars<<<1, 256, 0, stream>>>(colsum, Wf, bfp, pmem, cmom, tstep, sc);
    k_csef<<<4096, 256, 0, stream>>>(Wamp, colsum, bamp, cw, cstate, sc, csef);
    gemm256<1><<<512, 512, 0, stream>>>(x_bf, wg_bf, x, bgate, csef, sc, enh_bf, nullptr);
    gemm256<2><<<512, 512, 0, stream>>>(enh_bf, wt_bf, nullptr, btemp, nullptr, sc, nullptr, out);
}